// Round 7
// baseline (295.464 us; speedup 1.0000x reference)
//
#include <hip/hip_runtime.h>
#include <hip/hip_bf16.h>
#include <math.h>

// Problem constants (fixed instance)
#define NTOK 2048
#define DIM 512
#define NCEN 500
#define NHEAD 8
#define HD 64
#define KWIN 128
#define DEPTH 8

// ---------------- workspace layout (bytes) ----------------
// cen    f64 [512][512]     @ 0          (2 MB) row-major [c][d], rows>=500 zero
// codes  i32 [2048]         @ 2097152
// P      i32 [257]          @ 2105344
// bidx   i32 [2048]         @ 2106400
// routes i32 [2048][128]    @ 2115584    (1 MB) -- region also hosts (dead before routes written):
//   pmax  f64 [8][2048]     @ 2115584    (131072)   written by simsgemm, read by codes3
//   hist  i32 [8][256]      @ 2115584    (8192)     after codes3: hist/scan (overwrites pmax head)
//   choff i32 [8][256]      @ 2123776    (8192)
// qkv    f32 [2048][1536]   @ 3164160    (12 MB)
// Obuf   f32 [2048][512]    @ 15747072   (4 MB)    end 19941376

// ------------------------------------------------------------------
// K1: centroid means, row-major f64. cen[c][d] = mean_v p[c][v][d]; c>=500 -> 0
__global__ __launch_bounds__(256) void centroids_k(const float* __restrict__ p,
                                                   double* __restrict__ cen) {
    int c = blockIdx.x;
    for (int d = threadIdx.x; d < DIM; d += 256) {
        double s = 0.0;
        if (c < NCEN) {
            const float* pc = p + (size_t)c * 5 * DIM;
            s  = (double)pc[0 * DIM + d];
            s += (double)pc[1 * DIM + d];
            s += (double)pc[2 * DIM + d];
            s += (double)pc[3 * DIM + d];
            s += (double)pc[4 * DIM + d];
            s = s / 5.0;
        }
        cen[(size_t)c * DIM + d] = s;
    }
}

// ------------------------------------------------------------------
// K2a: tiled f64 GEMM S = x * cen^T with fused max-over-ctile epilogue.
// grid (8 ctiles, 32 ttiles) x 256 threads. Tile 64 tok x 64 cen, K-chunk 32.
// Xs staged as f32 (x IS f32 -> lossless), converted to f64 on consume.
// Pads: Xs [32][69] (stride%32=5 -> ~2-way store banks), Cs [32][67].
__global__ __launch_bounds__(256) void simsgemm_k(const float* __restrict__ x,
                                                  const double* __restrict__ cen,
                                                  double* __restrict__ pmax) {
    __shared__ float  Xs[32][69];   // 8832 B
    __shared__ double Cs[32][67];   // 17152 B
    int tid = threadIdx.x;
    int c0 = blockIdx.x * 64;
    int t0 = blockIdx.y * 64;
    int tm = tid & 15, tn = tid >> 4;

    double acc[4][4] = {};
    for (int k0 = 0; k0 < DIM; k0 += 32) {
        // stage X: 64 tok x 32 k, f32
#pragma unroll
        for (int i = 0; i < 2; ++i) {
            int f = i * 256 + tid;
            int r = f >> 3, c4 = (f & 7) * 4;
            float4 va = *(const float4*)(x + (size_t)(t0 + r) * DIM + k0 + c4);
            Xs[c4 + 0][r] = va.x; Xs[c4 + 1][r] = va.y;
            Xs[c4 + 2][r] = va.z; Xs[c4 + 3][r] = va.w;
        }
        // stage C: 64 cen x 32 k, f64
#pragma unroll
        for (int i = 0; i < 4; ++i) {
            int u = i * 256 + tid;
            int r = u >> 4, kk = (u & 15) * 2;
            double2 vc = *(const double2*)(cen + (size_t)(c0 + r) * DIM + k0 + kk);
            Cs[kk][r] = vc.x; Cs[kk + 1][r] = vc.y;
        }
        __syncthreads();
#pragma unroll 4
        for (int k = 0; k < 32; ++k) {
            double am[4], bn[4];
#pragma unroll
            for (int i = 0; i < 4; ++i) am[i] = (double)Xs[k][tm + 16 * i];
#pragma unroll
            for (int j = 0; j < 4; ++j) bn[j] = Cs[k][tn + 16 * j];
#pragma unroll
            for (int i = 0; i < 4; ++i)
#pragma unroll
                for (int j = 0; j < 4; ++j) acc[i][j] += am[i] * bn[j];
        }
        __syncthreads();
    }

    // fused epilogue: max over this thread's valid cens, cross-tn reduce via Cs
    double (*red)[67] = Cs;   // reuse (all reads done, past last sync)
#pragma unroll
    for (int i = 0; i < 4; ++i) {
        double m = -1e300;
#pragma unroll
        for (int j = 0; j < 4; ++j) {
            bool valid = (c0 + tn + 16 * j) < NCEN;
            double v = valid ? acc[i][j] : -1e300;
            m = fmax(m, v);
        }
        red[tn][tm + 16 * i] = m;
    }
    __syncthreads();
    if (tid < 64) {
        double m = red[0][tid];
#pragma unroll
        for (int g = 1; g < 16; ++g) m = fmax(m, red[g][tid]);
        pmax[(size_t)blockIdx.x * NTOK + t0 + tid] = m;
    }
}

// ------------------------------------------------------------------
// K2b: merged norm + cantor codes. One wave per token; 512 blocks x 256.
__global__ __launch_bounds__(256) void codes3_k(const float* __restrict__ x,
                                                const double* __restrict__ pmax,
                                                const float* __restrict__ gwp,
                                                int* __restrict__ codes) {
    int tid = threadIdx.x;
    int lane = tid & 63;
    int w = tid >> 6;
    int n = blockIdx.x * 4 + w;

    // f64 norm of x row, in-register
    const float* xr = x + (size_t)n * DIM;
    double ss = 0.0;
#pragma unroll
    for (int i = 0; i < 8; ++i) {
        double v = (double)xr[lane + i * 64];
        ss += v * v;
    }
#pragma unroll
    for (int m = 32; m; m >>= 1) ss += __shfl_xor(ss, m);

    // reduce pmax over the 8 ctiles
    double m = (lane < 8) ? pmax[(size_t)lane * NTOK + n] : -1e300;
    m = fmax(m, __shfl_xor(m, 4));
    m = fmax(m, __shfl_xor(m, 2));
    m = fmax(m, __shfl_xor(m, 1));

    if (lane == 0) {
        double nrm = sqrt(ss) + 1e-12;
        double sims = m / nrm;
        double gwv = 1.0 / (1.0 + exp(-(double)gwp[0]));
        const double delta = 1.0 / 2047.0;
        double gd = 1.0 - sims;
        double pos = (n == NTOK - 1) ? 1.0 : (double)n * delta;
        double xc = pos * (1.0 - gwv) + gd * gwv;
        xc = fmin(fmax(xc, 1e-6), 1.0 - 1e-6);
        int code = 0;
#pragma unroll
        for (int l = 0; l < DEPTH; ++l) {
            double s3 = xc * 3.0;
            double dig = floor(s3);
            if (dig == 2.0) code |= 1 << (7 - l);
            xc = s3 - dig;
        }
        codes[n] = code;
    }
}

// ------------------------------------------------------------------
// K3a: per-chunk histogram. 8 blocks x 256.
__global__ __launch_bounds__(256) void hist_k(const int* __restrict__ codes,
                                              int* __restrict__ hist) {
    __shared__ int hl[256];
    int tid = threadIdx.x;
    hl[tid] = 0;
    __syncthreads();
    int c = codes[blockIdx.x * 256 + tid];
    atomicAdd(&hl[c], 1);
    __syncthreads();
    hist[blockIdx.x * 256 + tid] = hl[tid];
}

// K3b: scan -> P[257] and per-chunk offsets. 1 block x 256.
__global__ __launch_bounds__(256) void scan_k(const int* __restrict__ hist,
                                              int* __restrict__ P,
                                              int* __restrict__ chunkoff) {
    __shared__ int sc[256];
    int c = threadIdx.x;
    int h[8];
    int t = 0;
#pragma unroll
    for (int b = 0; b < 8; ++b) { h[b] = hist[b * 256 + c]; t += h[b]; }
    sc[c] = t;
    __syncthreads();
    for (int off = 1; off < 256; off <<= 1) {
        int v = sc[c];
        int add = (c >= off) ? sc[c - off] : 0;
        __syncthreads();
        sc[c] = v + add;
        __syncthreads();
    }
    int incl = sc[c];
    int base = incl - t;
    P[c] = base;
    if (c == 255) P[256] = incl;   // == 2048
    int pre = base;
#pragma unroll
    for (int b = 0; b < 8; ++b) { chunkoff[b * 256 + c] = pre; pre += h[b]; }
}

// K3c: stable scatter. 8 blocks x 256.
__global__ __launch_bounds__(256) void scatter_k(const int* __restrict__ codes,
                                                 const int* __restrict__ chunkoff,
                                                 int* __restrict__ bidx) {
    __shared__ int cl[256];
    int tid = threadIdx.x;
    int b = blockIdx.x;
    int idx = b * 256 + tid;
    int c = codes[idx];
    cl[tid] = c;
    __syncthreads();
    int rank = 0;
    for (int j = 0; j < tid; ++j) rank += (cl[j] == c) ? 1 : 0;
    bidx[chunkoff[b * 256 + c] + rank] = idx;
}

// ------------------------------------------------------------------
// K4: routes, one wave per query. Exact top-k set (order-free).
__global__ __launch_bounds__(256) void routes2_k(const int* __restrict__ codes,
                                                 const int* __restrict__ P,
                                                 const int* __restrict__ bidx,
                                                 int* __restrict__ routes) {
    int tid = threadIdx.x;
    int lane = tid & 63;
    int w = tid >> 6;
    int q = blockIdx.x * 4 + w;
    int ci = codes[q];

    int dstar = -1;
    for (int r = 0; r < 4 && dstar < 0; ++r) {
        int d = r * 64 + lane;
        int loc = ci - d; if (loc < 0) loc = 0;
        int hic = ci + d; if (hic > 255) hic = 255;
        int cum = P[hic + 1] - P[loc];
        unsigned long long m = __ballot(cum >= KWIN);
        if (m) dstar = r * 64 + (int)__builtin_ctzll(m);
    }

    int a = ci - dstar + 1; if (a < 0) a = 0;
    int b = ci + dstar - 1; if (b > 255) b = 255;
    int inner = 0, baseA = 0;
    if (dstar > 0) { baseA = P[a]; inner = P[b + 1] - baseA; }
    int rem = KWIN - inner;
    int* rq = routes + (size_t)q * KWIN;

    for (int t = lane; t < inner; t += 64) rq[t] = bidx[baseA + t];

    int lo = ci - dstar, hi = ci + dstar;
    int loS = 0, loL = 0, hiS = 0, hiL = 0;
    if (lo >= 0) { loS = P[lo]; loL = P[lo + 1] - loS; }
    if (dstar > 0 && hi <= 255) { hiS = P[hi]; hiL = P[hi + 1] - hiS; }

    int minI = rem - hiL; if (minI < 0) minI = 0;
    int maxI = (rem < loL) ? rem : loL;
    int ans = minI;
    int loI = minI, hiI = maxI;
    for (int it = 0; it < 12 && loI <= hiI; ++it) {
        int i = (loI + hiI) >> 1;
        int j = rem - i;
        bool tooMany = (i > 0 && j < hiL && bidx[loS + i - 1] > bidx[hiS + j]);
        bool tooFew  = (j > 0 && i < loL && bidx[hiS + j - 1] > bidx[loS + i]);
        if (tooMany) hiI = i - 1;
        else if (tooFew) loI = i + 1;
        else { ans = i; break; }
    }
    int ilo = ans;
    int jn = rem - ilo;
    for (int t = lane; t < ilo; t += 64) rq[inner + t] = bidx[loS + t];
    for (int t = lane; t < jn; t += 64) rq[inner + ilo + t] = bidx[hiS + t];
}

// ------------------------------------------------------------------
// K5: C[M][Nn] = A[M][512] * B[Nn][512]^T + bias   (f32, 64x64 tile, proven)
__global__ __launch_bounds__(256) void gemm_nt_bias(const float* __restrict__ A,
                                                    const float* __restrict__ Bw,
                                                    const float* __restrict__ bias,
                                                    float* __restrict__ Cc,
                                                    int M, int Nn) {
    __shared__ float As[32][68];
    __shared__ float Bs[32][68];
    int tid = threadIdx.x;
    int n0 = blockIdx.x * 64;
    int m0 = blockIdx.y * 64;
    int tm = tid & 15, tn = tid >> 4;
    float acc[4][4] = {};
    for (int k0 = 0; k0 < 512; k0 += 32) {
#pragma unroll
        for (int i = 0; i < 2; ++i) {
            int f = i * 256 + tid;
            int r = f >> 3, c4 = (f & 7) * 4;
            float4 va = *(const float4*)(A + (size_t)(m0 + r) * 512 + k0 + c4);
            As[c4 + 0][r] = va.x; As[c4 + 1][r] = va.y;
            As[c4 + 2][r] = va.z; As[c4 + 3][r] = va.w;
            float4 vb = *(const float4*)(Bw + (size_t)(n0 + r) * 512 + k0 + c4);
            Bs[c4 + 0][r] = vb.x; Bs[c4 + 1][r] = vb.y;
            Bs[c4 + 2][r] = vb.z; Bs[c4 + 3][r] = vb.w;
        }
        __syncthreads();
#pragma unroll
        for (int k = 0; k < 32; ++k) {
            float4 a4 = *(const float4*)&As[k][tm * 4];
            float4 b4 = *(const float4*)&Bs[k][tn * 4];
            float av[4] = {a4.x, a4.y, a4.z, a4.w};
            float bv[4] = {b4.x, b4.y, b4.z, b4.w};
#pragma unroll
            for (int i = 0; i < 4; ++i)
#pragma unroll
                for (int j = 0; j < 4; ++j) acc[i][j] += av[i] * bv[j];
        }
        __syncthreads();
    }
#pragma unroll
    for (int i = 0; i < 4; ++i) {
        int m = m0 + tm * 4 + i;
        int n = n0 + tn * 4;
        float4 o;
        o.x = acc[i][0] + bias[n + 0];
        o.y = acc[i][1] + bias[n + 1];
        o.z = acc[i][2] + bias[n + 2];
        o.w = acc[i][3] + bias[n + 3];
        *(float4*)(Cc + (size_t)m * Nn + n) = o;
    }
}

// ------------------------------------------------------------------
// K6: sparse attention, row-streaming. 1 block = 1 query (Cantor-sorted order,
// XCD-chunked). 256 threads = 4 waves; wave w owns route slots [w*32,w*32+32).
__global__ __launch_bounds__(256) void attn_v3(const float* __restrict__ qkv,
                                               const int* __restrict__ bidx,
                                               const int* __restrict__ routes,
                                               float* __restrict__ Obuf) {
    __shared__ int rt[KWIN];
    __shared__ float sc[NHEAD][KWIN];
    __shared__ float part[4][DIM];
    int tid = threadIdx.x;
    int lane = tid & 63;
    int w = tid >> 6;

    int b = blockIdx.x;
    int ord = (b & 7) * 256 + (b >> 3);    // XCD-chunked, bijective on [0,2048)
    int q = bidx[ord];

    if (tid < KWIN) rt[tid] = routes[(size_t)q * KWIN + tid];

    const float* qrow = qkv + (size_t)q * 1536 + lane * 8;
    float4 qa = *(const float4*)(qrow);
    float4 qb = *(const float4*)(qrow + 4);
    __syncthreads();

#pragma unroll 4
    for (int i = 0; i < 32; ++i) {
        int kk = w * 32 + i;
        int j = rt[kk];
        const float* kp = qkv + (size_t)j * 1536 + 512 + lane * 8;
        float4 k0 = *(const float4*)(kp);
        float4 k1 = *(const float4*)(kp + 4);
        float s = qa.x * k0.x + qa.y * k0.y + qa.z * k0.z + qa.w * k0.w
                + qb.x * k1.x + qb.y * k1.y + qb.z * k1.z + qb.w * k1.w;
        s += __shfl_xor(s, 1);
        s += __shfl_xor(s, 2);
        s += __shfl_xor(s, 4);
        if ((lane & 7) == 0) sc[lane >> 3][kk] = s * 0.125f;
    }
    __syncthreads();

    {
        int g = tid >> 5, l = tid & 31;
        float v0 = sc[g][l], v1 = sc[g][l + 32], v2 = sc[g][l + 64], v3 = sc[g][l + 96];
        float mx = fmaxf(fmaxf(v0, v1), fmaxf(v2, v3));
        for (int m = 16; m; m >>= 1) mx = fmaxf(mx, __shfl_xor(mx, m, 32));
        float e0 = expf(v0 - mx), e1 = expf(v1 - mx),
              e2 = expf(v2 - mx), e3 = expf(v3 - mx);
        float sum = e0 + e1 + e2 + e3;
        for (int m = 16; m; m >>= 1) sum += __shfl_xor(sum, m, 32);
        float inv = 1.f / sum;
        sc[g][l] = e0 * inv; sc[g][l + 32] = e1 * inv;
        sc[g][l + 64] = e2 * inv; sc[g][l + 96] = e3 * inv;
    }
    __syncthreads();

    float acc[8] = {0.f, 0.f, 0.f, 0.f, 0.f, 0.f, 0.f, 0.f};
    const float* sch = sc[lane >> 3];
#pragma unroll 4
    for (int i = 0; i < 32; ++i) {
        int kk = w * 32 + i;
        int j = rt[kk];
        float wgt = sch[kk];
        const float* vp = qkv + (size_t)j * 1536 + 1024 + lane * 8;
        float4 v0 = *(const float4*)(vp);
        float4 v1 = *(const float4*)(vp + 4);
        acc[0] += wgt * v0.x; acc[1] += wgt * v0.y;
        acc[2] += wgt * v0.z; acc[3] += wgt * v0.w;
        acc[4] += wgt * v1.x; acc[5] += wgt * v1.y;
        acc[6] += wgt * v1.z; acc[7] += wgt * v1.w;
    }
#pragma unroll
    for (int e = 0; e < 8; ++e) part[w][lane * 8 + e] = acc[e];
    __syncthreads();

#pragma unroll
    for (int r = 0; r < 2; ++r) {
        int d = r * 256 + tid;
        float o = part[0][d] + part[1][d] + part[2][d] + part[3][d];
        Obuf[(size_t)q * DIM + d] = o;
    }
}

// ------------------------------------------------------------------
extern "C" void kernel_launch(void* const* d_in, const int* in_sizes, int n_in,
                              void* d_out, int out_size, void* d_ws, size_t ws_size,
                              hipStream_t stream) {
    const float* x      = (const float*)d_in[0];
    const float* penta  = (const float*)d_in[1];
    const float* w_qkv  = (const float*)d_in[2];
    const float* b_qkv  = (const float*)d_in[3];
    const float* w_out  = (const float*)d_in[4];
    const float* b_out  = (const float*)d_in[5];
    const float* gw     = (const float*)d_in[6];
    float* out = (float*)d_out;
    char* ws = (char*)d_ws;

    double* cen   = (double*)(ws + 0);
    int* codes    = (int*)(ws + 2097152);
    int* P        = (int*)(ws + 2105344);
    int* bidx     = (int*)(ws + 2106400);
    int* routes   = (int*)(ws + 2115584);
    // overlapped in routes region (all dead before routes2_k writes routes):
    double* pmax  = (double*)(ws + 2115584);   // [8][2048] f64
    int* hist     = (int*)(ws + 2115584);      // after codes3 done
    int* chunkoff = (int*)(ws + 2123776);
    float* qkv    = (float*)(ws + 3164160);
    float* Obuf   = (float*)(ws + 15747072);

    centroids_k<<<512, 256, 0, stream>>>(penta, cen);
    simsgemm_k<<<dim3(8, 32), 256, 0, stream>>>(x, cen, pmax);
    codes3_k<<<512, 256, 0, stream>>>(x, pmax, gw, codes);
    hist_k<<<8, 256, 0, stream>>>(codes, hist);
    scan_k<<<1, 256, 0, stream>>>(hist, P, chunkoff);
    scatter_k<<<8, 256, 0, stream>>>(codes, chunkoff, bidx);
    gemm_nt_bias<<<dim3(1536 / 64, 2048 / 64), 256, 0, stream>>>(x, w_qkv, b_qkv, qkv, NTOK, 1536);
    routes2_k<<<512, 256, 0, stream>>>(codes, P, bidx, routes);
    attn_v3<<<NTOK, 256, 0, stream>>>(qkv, bidx, routes, Obuf);
    gemm_nt_bias<<<dim3(512 / 64, 2048 / 64), 256, 0, stream>>>(Obuf, w_out, b_out, out, NTOK, 512);
}

// Round 9
// 224.532 us; speedup vs baseline: 1.3159x; 1.3159x over previous
//
#include <hip/hip_runtime.h>
#include <hip/hip_bf16.h>
#include <math.h>

// Problem constants (fixed instance)
#define NTOK 2048
#define DIM 512
#define NCEN 500
#define NHEAD 8
#define HD 64
#define KWIN 128
#define DEPTH 8

typedef __attribute__((ext_vector_type(8))) short bf16x8;
typedef __attribute__((ext_vector_type(4))) float f32x4;

// ---------------- workspace layout (bytes) ----------------
// cen    f64 [512][512]     @ 0          (2 MB) row-major [c][d], rows>=500 zero
// codes  i32 [2048]         @ 2097152
// P      i32 [257]          @ 2105344
// bidx   i32 [2048]         @ 2106400
// routes i32 [2048][128]    @ 2115584    (1 MB) -- region also hosts (dead before routes written):
//   pmax  f64 [8][2048]     @ 2115584    (131072)  written by simsgemm, read by codes3
//   hist  i32 [8][256]      @ 2115584    (8192)    after codes3: hist/scan
//   choff i32 [8][256]      @ 2123776    (8192)
// qkv    f32 [2048][1536]   @ 3164160    (12 MB)
// Obuf   f32 [2048][512]    @ 15747072   (4 MB)    end 19941376

// ------------------------------------------------------------------
// K1: centroid means, row-major f64. cen[c][d] = mean_v p[c][v][d]; c>=500 -> 0
__global__ __launch_bounds__(256) void centroids_k(const float* __restrict__ p,
                                                   double* __restrict__ cen) {
    int c = blockIdx.x;
    for (int d = threadIdx.x; d < DIM; d += 256) {
        double s = 0.0;
        if (c < NCEN) {
            const float* pc = p + (size_t)c * 5 * DIM;
            s  = (double)pc[0 * DIM + d];
            s += (double)pc[1 * DIM + d];
            s += (double)pc[2 * DIM + d];
            s += (double)pc[3 * DIM + d];
            s += (double)pc[4 * DIM + d];
            s = s / 5.0;
        }
        cen[(size_t)c * DIM + d] = s;
    }
}

// ------------------------------------------------------------------
// K2a: tiled f64 GEMM S = x * cen^T, fused max epilogue (R4-proven structure,
// f64 staging — no inner-loop converts; [67] pads for ~2-way store banks).
__global__ __launch_bounds__(256) void simsgemm_k(const float* __restrict__ x,
                                                  const double* __restrict__ cen,
                                                  double* __restrict__ pmax) {
    __shared__ double Xs[32][67];
    __shared__ double Cs[32][67];
    int tid = threadIdx.x;
    int c0 = blockIdx.x * 64;
    int t0 = blockIdx.y * 64;
    int tm = tid & 15, tn = tid >> 4;

    double acc[4][4] = {};
    for (int k0 = 0; k0 < DIM; k0 += 32) {
#pragma unroll
        for (int i = 0; i < 2; ++i) {
            int f = i * 256 + tid;
            int r = f >> 3, c4 = (f & 7) * 4;
            float4 va = *(const float4*)(x + (size_t)(t0 + r) * DIM + k0 + c4);
            Xs[c4 + 0][r] = (double)va.x; Xs[c4 + 1][r] = (double)va.y;
            Xs[c4 + 2][r] = (double)va.z; Xs[c4 + 3][r] = (double)va.w;
        }
#pragma unroll
        for (int i = 0; i < 4; ++i) {
            int u = i * 256 + tid;
            int r = u >> 4, kk = (u & 15) * 2;
            double2 vc = *(const double2*)(cen + (size_t)(c0 + r) * DIM + k0 + kk);
            Cs[kk][r] = vc.x; Cs[kk + 1][r] = vc.y;
        }
        __syncthreads();
#pragma unroll 4
        for (int k = 0; k < 32; ++k) {
            double am[4], bn[4];
#pragma unroll
            for (int i = 0; i < 4; ++i) am[i] = Xs[k][tm + 16 * i];
#pragma unroll
            for (int j = 0; j < 4; ++j) bn[j] = Cs[k][tn + 16 * j];
#pragma unroll
            for (int i = 0; i < 4; ++i)
#pragma unroll
                for (int j = 0; j < 4; ++j) acc[i][j] += am[i] * bn[j];
        }
        __syncthreads();
    }

    double (*red)[67] = Xs;   // reuse (past last sync)
#pragma unroll
    for (int i = 0; i < 4; ++i) {
        double m = -1e300;
#pragma unroll
        for (int j = 0; j < 4; ++j) {
            bool valid = (c0 + tn + 16 * j) < NCEN;
            double v = valid ? acc[i][j] : -1e300;
            m = fmax(m, v);
        }
        red[tn][tm + 16 * i] = m;
    }
    __syncthreads();
    if (tid < 64) {
        double m = red[0][tid];
#pragma unroll
        for (int g = 1; g < 16; ++g) m = fmax(m, red[g][tid]);
        pmax[(size_t)blockIdx.x * NTOK + t0 + tid] = m;
    }
}

// ------------------------------------------------------------------
// K2b: merged norm + cantor codes. One wave per token; 512 blocks x 256.
__global__ __launch_bounds__(256) void codes3_k(const float* __restrict__ x,
                                                const double* __restrict__ pmax,
                                                const float* __restrict__ gwp,
                                                int* __restrict__ codes) {
    int tid = threadIdx.x;
    int lane = tid & 63;
    int w = tid >> 6;
    int n = blockIdx.x * 4 + w;

    const float* xr = x + (size_t)n * DIM;
    double ss = 0.0;
#pragma unroll
    for (int i = 0; i < 8; ++i) {
        double v = (double)xr[lane + i * 64];
        ss += v * v;
    }
#pragma unroll
    for (int m = 32; m; m >>= 1) ss += __shfl_xor(ss, m);

    double m = (lane < 8) ? pmax[(size_t)lane * NTOK + n] : -1e300;
    m = fmax(m, __shfl_xor(m, 4));
    m = fmax(m, __shfl_xor(m, 2));
    m = fmax(m, __shfl_xor(m, 1));

    if (lane == 0) {
        double nrm = sqrt(ss) + 1e-12;
        double sims = m / nrm;
        double gwv = 1.0 / (1.0 + exp(-(double)gwp[0]));
        const double delta = 1.0 / 2047.0;
        double gd = 1.0 - sims;
        double pos = (n == NTOK - 1) ? 1.0 : (double)n * delta;
        double xc = pos * (1.0 - gwv) + gd * gwv;
        xc = fmin(fmax(xc, 1e-6), 1.0 - 1e-6);
        int code = 0;
#pragma unroll
        for (int l = 0; l < DEPTH; ++l) {
            double s3 = xc * 3.0;
            double dig = floor(s3);
            if (dig == 2.0) code |= 1 << (7 - l);
            xc = s3 - dig;
        }
        codes[n] = code;
    }
}

// ------------------------------------------------------------------
// K3a: per-chunk histogram. 8 blocks x 256.
__global__ __launch_bounds__(256) void hist_k(const int* __restrict__ codes,
                                              int* __restrict__ hist) {
    __shared__ int hl[256];
    int tid = threadIdx.x;
    hl[tid] = 0;
    __syncthreads();
    int c = codes[blockIdx.x * 256 + tid];
    atomicAdd(&hl[c], 1);
    __syncthreads();
    hist[blockIdx.x * 256 + tid] = hl[tid];
}

// K3b: scan -> P[257] and per-chunk offsets. 1 block x 256.
__global__ __launch_bounds__(256) void scan_k(const int* __restrict__ hist,
                                              int* __restrict__ P,
                                              int* __restrict__ chunkoff) {
    __shared__ int sc[256];
    int c = threadIdx.x;
    int h[8];
    int t = 0;
#pragma unroll
    for (int b = 0; b < 8; ++b) { h[b] = hist[b * 256 + c]; t += h[b]; }
    sc[c] = t;
    __syncthreads();
    for (int off = 1; off < 256; off <<= 1) {
        int v = sc[c];
        int add = (c >= off) ? sc[c - off] : 0;
        __syncthreads();
        sc[c] = v + add;
        __syncthreads();
    }
    int incl = sc[c];
    int base = incl - t;
    P[c] = base;
    if (c == 255) P[256] = incl;   // == 2048
    int pre = base;
#pragma unroll
    for (int b = 0; b < 8; ++b) { chunkoff[b * 256 + c] = pre; pre += h[b]; }
}

// K3c: stable scatter. 8 blocks x 256.
__global__ __launch_bounds__(256) void scatter_k(const int* __restrict__ codes,
                                                 const int* __restrict__ chunkoff,
                                                 int* __restrict__ bidx) {
    __shared__ int cl[256];
    int tid = threadIdx.x;
    int b = blockIdx.x;
    int idx = b * 256 + tid;
    int c = codes[idx];
    cl[tid] = c;
    __syncthreads();
    int rank = 0;
    for (int j = 0; j < tid; ++j) rank += (cl[j] == c) ? 1 : 0;
    bidx[chunkoff[b * 256 + c] + rank] = idx;
}

// ------------------------------------------------------------------
// K4: routes, one wave per query. Exact top-k set (order-free).
__global__ __launch_bounds__(256) void routes2_k(const int* __restrict__ codes,
                                                 const int* __restrict__ P,
                                                 const int* __restrict__ bidx,
                                                 int* __restrict__ routes) {
    int tid = threadIdx.x;
    int lane = tid & 63;
    int w = tid >> 6;
    int q = blockIdx.x * 4 + w;
    int ci = codes[q];

    int dstar = -1;
    for (int r = 0; r < 4 && dstar < 0; ++r) {
        int d = r * 64 + lane;
        int loc = ci - d; if (loc < 0) loc = 0;
        int hic = ci + d; if (hic > 255) hic = 255;
        int cum = P[hic + 1] - P[loc];
        unsigned long long m = __ballot(cum >= KWIN);
        if (m) dstar = r * 64 + (int)__builtin_ctzll(m);
    }

    int a = ci - dstar + 1; if (a < 0) a = 0;
    int b = ci + dstar - 1; if (b > 255) b = 255;
    int inner = 0, baseA = 0;
    if (dstar > 0) { baseA = P[a]; inner = P[b + 1] - baseA; }
    int rem = KWIN - inner;
    int* rq = routes + (size_t)q * KWIN;

    for (int t = lane; t < inner; t += 64) rq[t] = bidx[baseA + t];

    int lo = ci - dstar, hi = ci + dstar;
    int loS = 0, loL = 0, hiS = 0, hiL = 0;
    if (lo >= 0) { loS = P[lo]; loL = P[lo + 1] - loS; }
    if (dstar > 0 && hi <= 255) { hiS = P[hi]; hiL = P[hi + 1] - hiS; }

    int minI = rem - hiL; if (minI < 0) minI = 0;
    int maxI = (rem < loL) ? rem : loL;
    int ans = minI;
    int loI = minI, hiI = maxI;
    for (int it = 0; it < 12 && loI <= hiI; ++it) {
        int i = (loI + hiI) >> 1;
        int j = rem - i;
        bool tooMany = (i > 0 && j < hiL && bidx[loS + i - 1] > bidx[hiS + j]);
        bool tooFew  = (j > 0 && i < loL && bidx[hiS + j - 1] > bidx[loS + i]);
        if (tooMany) hiI = i - 1;
        else if (tooFew) loI = i + 1;
        else { ans = i; break; }
    }
    int ilo = ans;
    int jn = rem - ilo;
    for (int t = lane; t < ilo; t += 64) rq[inner + t] = bidx[loS + t];
    for (int t = lane; t < jn; t += 64) rq[inner + ilo + t] = bidx[hiS + t];
}

// ------------------------------------------------------------------
// K5: split-precision bf16x2 MFMA GEMM.  C[M][Nn] = A[M][512]*B[Nn][512]^T + bias
// A = A_hi + A_lo (bf16 each, split in staging); D accumulates
// Ahi*Bhi + Ahi*Blo + Alo*Bhi in f32 MFMA — error ~ lo*lo ~ 1.5e-5 rel.
// Block: 256 thr / 4 waves; tile 64x64; wave w owns rows [w*16,w*16+16).
// grid (Nn/64, M/64).
__global__ __launch_bounds__(256) void gemm_mfma_k(const float* __restrict__ A,
                                                   const float* __restrict__ Bw,
                                                   const float* __restrict__ bias,
                                                   float* __restrict__ Cc,
                                                   int Nn) {
    __shared__ ushort Ahi[64][40], Alo[64][40];   // 40-pad: rows 80B (16B-aligned, ~2-way banks)
    __shared__ ushort Bhi[64][40], Blo[64][40];
    int tid = threadIdx.x;
    int lane = tid & 63;
    int w = tid >> 6;
    int n0 = blockIdx.x * 64;
    int m0 = blockIdx.y * 64;
    int r = tid >> 2, q = tid & 3;        // staging: row, k-quarter (8 elems)
    int l15 = lane & 15, l4 = lane >> 4;

    f32x4 acc[4];
#pragma unroll
    for (int nt = 0; nt < 4; ++nt) acc[nt] = (f32x4){0.f, 0.f, 0.f, 0.f};

    for (int k0 = 0; k0 < 512; k0 += 32) {
        // stage A row r, 8 elems at k0+q*8 (f32 -> hi/lo bf16)
        {
            const float* src = A + (size_t)(m0 + r) * 512 + k0 + q * 8;
            ushort h8[8], l8[8];
#pragma unroll
            for (int e = 0; e < 8; ++e) {
                float v = src[e];
                __hip_bfloat16 hb = __float2bfloat16(v);
                float hf = __bfloat162float(hb);
                __hip_bfloat16 lb = __float2bfloat16(v - hf);
                h8[e] = *reinterpret_cast<ushort*>(&hb);
                l8[e] = *reinterpret_cast<ushort*>(&lb);
            }
            *(uint4*)&Ahi[r][q * 8] = *(uint4*)h8;
            *(uint4*)&Alo[r][q * 8] = *(uint4*)l8;
        }
        {
            const float* src = Bw + (size_t)(n0 + r) * 512 + k0 + q * 8;
            ushort h8[8], l8[8];
#pragma unroll
            for (int e = 0; e < 8; ++e) {
                float v = src[e];
                __hip_bfloat16 hb = __float2bfloat16(v);
                float hf = __bfloat162float(hb);
                __hip_bfloat16 lb = __float2bfloat16(v - hf);
                h8[e] = *reinterpret_cast<ushort*>(&hb);
                l8[e] = *reinterpret_cast<ushort*>(&lb);
            }
            *(uint4*)&Bhi[r][q * 8] = *(uint4*)h8;
            *(uint4*)&Blo[r][q * 8] = *(uint4*)l8;
        }
        __syncthreads();

        bf16x8 ah = *(const bf16x8*)&Ahi[w * 16 + l15][l4 * 8];
        bf16x8 al = *(const bf16x8*)&Alo[w * 16 + l15][l4 * 8];
#pragma unroll
        for (int nt = 0; nt < 4; ++nt) {
            bf16x8 bh = *(const bf16x8*)&Bhi[nt * 16 + l15][l4 * 8];
            bf16x8 bl = *(const bf16x8*)&Blo[nt * 16 + l15][l4 * 8];
            acc[nt] = __builtin_amdgcn_mfma_f32_16x16x32_bf16(ah, bh, acc[nt], 0, 0, 0);
            acc[nt] = __builtin_amdgcn_mfma_f32_16x16x32_bf16(ah, bl, acc[nt], 0, 0, 0);
            acc[nt] = __builtin_amdgcn_mfma_f32_16x16x32_bf16(al, bh, acc[nt], 0, 0, 0);
        }
        __syncthreads();
    }

    // C/D layout: col = lane&15, row = (lane>>4)*4 + reg   [m89-verified]
#pragma unroll
    for (int nt = 0; nt < 4; ++nt) {
        int col = n0 + nt * 16 + l15;
        float bv = bias[col];
#pragma unroll
        for (int rr = 0; rr < 4; ++rr) {
            int row = m0 + w * 16 + l4 * 4 + rr;
            Cc[(size_t)row * Nn + col] = acc[nt][rr] + bv;
        }
    }
}

// ------------------------------------------------------------------
// K6: sparse attention, row-streaming. 1 block = 1 query (Cantor-sorted order,
// XCD-chunked). 256 threads = 4 waves; wave w owns route slots [w*32,w*32+32).
__global__ __launch_bounds__(256) void attn_v3(const float* __restrict__ qkv,
                                               const int* __restrict__ bidx,
                                               const int* __restrict__ routes,
                                               float* __restrict__ Obuf) {
    __shared__ int rt[KWIN];
    __shared__ float sc[NHEAD][KWIN];
    __shared__ float part[4][DIM];
    int tid = threadIdx.x;
    int lane = tid & 63;
    int w = tid >> 6;

    int b = blockIdx.x;
    int ord = (b & 7) * 256 + (b >> 3);    // XCD-chunked, bijective on [0,2048)
    int q = bidx[ord];

    if (tid < KWIN) rt[tid] = routes[(size_t)q * KWIN + tid];

    const float* qrow = qkv + (size_t)q * 1536 + lane * 8;
    float4 qa = *(const float4*)(qrow);
    float4 qb = *(const float4*)(qrow + 4);
    __syncthreads();

#pragma unroll 4
    for (int i = 0; i < 32; ++i) {
        int kk = w * 32 + i;
        int j = rt[kk];
        const float* kp = qkv + (size_t)j * 1536 + 512 + lane * 8;
        float4 k0 = *(const float4*)(kp);
        float4 k1 = *(const float4*)(kp + 4);
        float s = qa.x * k0.x + qa.y * k0.y + qa.z * k0.z + qa.w * k0.w
                + qb.x * k1.x + qb.y * k1.y + qb.z * k1.z + qb.w * k1.w;
        s += __shfl_xor(s, 1);
        s += __shfl_xor(s, 2);
        s += __shfl_xor(s, 4);
        if ((lane & 7) == 0) sc[lane >> 3][kk] = s * 0.125f;
    }
    __syncthreads();

    {
        int g = tid >> 5, l = tid & 31;
        float v0 = sc[g][l], v1 = sc[g][l + 32], v2 = sc[g][l + 64], v3 = sc[g][l + 96];
        float mx = fmaxf(fmaxf(v0, v1), fmaxf(v2, v3));
        for (int m = 16; m; m >>= 1) mx = fmaxf(mx, __shfl_xor(mx, m, 32));
        float e0 = expf(v0 - mx), e1 = expf(v1 - mx),
              e2 = expf(v2 - mx), e3 = expf(v3 - mx);
        float sum = e0 + e1 + e2 + e3;
        for (int m = 16; m; m >>= 1) sum += __shfl_xor(sum, m, 32);
        float inv = 1.f / sum;
        sc[g][l] = e0 * inv; sc[g][l + 32] = e1 * inv;
        sc[g][l + 64] = e2 * inv; sc[g][l + 96] = e3 * inv;
    }
    __syncthreads();

    float acc[8] = {0.f, 0.f, 0.f, 0.f, 0.f, 0.f, 0.f, 0.f};
    const float* sch = sc[lane >> 3];
#pragma unroll 4
    for (int i = 0; i < 32; ++i) {
        int kk = w * 32 + i;
        int j = rt[kk];
        float wgt = sch[kk];
        const float* vp = qkv + (size_t)j * 1536 + 1024 + lane * 8;
        float4 v0 = *(const float4*)(vp);
        float4 v1 = *(const float4*)(vp + 4);
        acc[0] += wgt * v0.x; acc[1] += wgt * v0.y;
        acc[2] += wgt * v0.z; acc[3] += wgt * v0.w;
        acc[4] += wgt * v1.x; acc[5] += wgt * v1.y;
        acc[6] += wgt * v1.z; acc[7] += wgt * v1.w;
    }
#pragma unroll
    for (int e = 0; e < 8; ++e) part[w][lane * 8 + e] = acc[e];
    __syncthreads();

#pragma unroll
    for (int r = 0; r < 2; ++r) {
        int d = r * 256 + tid;
        float o = part[0][d] + part[1][d] + part[2][d] + part[3][d];
        Obuf[(size_t)q * DIM + d] = o;
    }
}

// ------------------------------------------------------------------
extern "C" void kernel_launch(void* const* d_in, const int* in_sizes, int n_in,
                              void* d_out, int out_size, void* d_ws, size_t ws_size,
                              hipStream_t stream) {
    const float* x      = (const float*)d_in[0];
    const float* penta  = (const float*)d_in[1];
    const float* w_qkv  = (const float*)d_in[2];
    const float* b_qkv  = (const float*)d_in[3];
    const float* w_out  = (const float*)d_in[4];
    const float* b_out  = (const float*)d_in[5];
    const float* gw     = (const float*)d_in[6];
    float* out = (float*)d_out;
    char* ws = (char*)d_ws;

    double* cen   = (double*)(ws + 0);
    int* codes    = (int*)(ws + 2097152);
    int* P        = (int*)(ws + 2105344);
    int* bidx     = (int*)(ws + 2106400);
    int* routes   = (int*)(ws + 2115584);
    // overlapped in routes region (all dead before routes2_k writes routes):
    double* pmax  = (double*)(ws + 2115584);   // [8][2048] f64
    int* hist     = (int*)(ws + 2115584);      // after codes3 done
    int* chunkoff = (int*)(ws + 2123776);
    float* qkv    = (float*)(ws + 3164160);
    float* Obuf   = (float*)(ws + 15747072);

    centroids_k<<<512, 256, 0, stream>>>(penta, cen);
    simsgemm_k<<<dim3(8, 32), 256, 0, stream>>>(x, cen, pmax);
    codes3_k<<<512, 256, 0, stream>>>(x, pmax, gw, codes);
    hist_k<<<8, 256, 0, stream>>>(codes, hist);
    scan_k<<<1, 256, 0, stream>>>(hist, P, chunkoff);
    scatter_k<<<8, 256, 0, stream>>>(codes, chunkoff, bidx);
    gemm_mfma_k<<<dim3(1536 / 64, 2048 / 64), 256, 0, stream>>>(x, w_qkv, b_qkv, qkv, 1536);
    routes2_k<<<512, 256, 0, stream>>>(codes, P, bidx, routes);
    attn_v3<<<NTOK, 256, 0, stream>>>(qkv, bidx, routes, Obuf);
    gemm_mfma_k<<<dim3(512 / 64, 2048 / 64), 256, 0, stream>>>(Obuf, w_out, b_out, out, 512);
}